// Round 1
// baseline (322.858 us; speedup 1.0000x reference)
//
#include <hip/hip_runtime.h>
#include <math.h>

// Problem constants (fixed by setup_inputs)
#define NB 2
#define NH 12
#define NW 12
#define NK 3
#define NI 32
#define NO 32
#define NA 16                 // a*a = 16 pose elements
#define NBHW (NB*NH*NW)       // 288 spatial positions
#define NC (NK*NK*NI)         // 288 children per position
#define CSTR (NO*NA)          // 512 floats per child (o-major, a-minor)
#define VPB (NC*CSTR)         // 147456 votes floats per bhw
#define HR 14
#define WR 14
#define EPSF 1e-7f
#define MINVAR 5e-4f
#define TEMP0 0.0005f         // 0.01*(1-0.95^1), m_step it=0
#define TEMPF 0.00142625f     // 0.01*(1-0.95^3), final m_step it=ITERATIONS=2

// Workspace layout (float offsets). Total ~11.9 MB.
#define MU_OFF 0              // [bhw][a][o]  147456
#define W_OFF  147456         // inv(2*sig)   147456
#define L_OFF  294912         // log(a_j)-sum log(2pi sig)  [bhw][o] 9216
#define BM_OFF 304128         // per-block max, 288
#define M_OFF  304416         // global max scalar
#define DENSE_OFF 304432      // [b][y'][x'][i] 12544
#define LOGNUM_OFF 316976     // [bhw][c][o] 2654208
#define DENSE_N (NB*HR*WR*NI)

// ---------------- Kernel A: m_step 1 (R uniform = 1/NO) ----------------
// grid = NBHW*2 (o-halves), block = 256, thread t = (o_loc<<4)|a
__global__ __launch_bounds__(256) void kA(const float* __restrict__ votes,
        const float* __restrict__ acts, const float* __restrict__ beta_a,
        const float* __restrict__ beta_u, float* __restrict__ ws) {
    __shared__ float s_acts[NC];
    const int bid = blockIdx.x;
    const int bhw = bid >> 1;
    const int obase = (bid & 1) * 16;
    const int t = threadIdx.x;
    const int a = t & 15;
    const int o = obase + (t >> 4);
    for (int idx = t; idx < NC; idx += 256) s_acts[idx] = acts[bhw*NC + idx];
    __syncthreads();
    const float* vb = votes + (size_t)bhw*VPB + obase*NA;  // +t -> (o_loc,a)
    float s1 = 0.f, s2 = 0.f, sumR = 0.f;
    #pragma unroll 4
    for (int c = 0; c < NC; ++c) {
        float v  = vb[(size_t)c*CSTR + t];      // contiguous 1KB per block/iter
        float ra = s_acts[c] * (1.0f/NO);
        float rv = ra * v;
        s1 += rv;
        s2 = fmaf(rv, v, s2);
        sumR += ra;
    }
    float mu  = s1 / (sumR + EPSF);
    float sig = (s2 - mu*(2.f*s1 - mu*sumR)) / (sumR + EPSF) + MINVAR;
    ws[MU_OFF + bhw*512 + a*32 + o] = mu;       // [a][o] layout for kB
    ws[W_OFF  + bhw*512 + a*32 + o] = 0.5f / sig;
    float cost = (beta_u[o] - 0.5f*logf(sig + EPSF)) * sumR;
    float ps   = logf(6.2831853071795864f * sig);
    #pragma unroll
    for (int d = 1; d < 16; d <<= 1) {
        cost += __shfl_xor(cost, d);
        ps   += __shfl_xor(ps, d);
    }
    if (a == 0) {
        float aj = 1.0f/(1.0f + expf(-TEMP0*(beta_a[o] - cost)));
        ws[L_OFF + bhw*32 + o] = logf(aj) - ps;   // log a_j + (-sum log 2pi sig)
    }
}

// ---------------- Kernel B: lognum + per-block max ----------------
// grid = NBHW, block = 256. o = t&31 is iteration-invariant -> hoist mu/w regs.
__global__ __launch_bounds__(256) void kB(const float* __restrict__ votes,
                                          float* __restrict__ ws) {
    const int bhw = blockIdx.x;
    const int t = threadIdx.x;
    const int o = t & 31;
    float mur[16], wr[16];
    const float* mup = ws + MU_OFF + bhw*512;
    const float* wp  = ws + W_OFF  + bhw*512;
    #pragma unroll
    for (int a = 0; a < 16; ++a) { mur[a] = mup[a*32+o]; wr[a] = wp[a*32+o]; }
    const float L = ws[L_OFF + bhw*32 + o];
    const float* vb = votes + (size_t)bhw*VPB;
    float* lp = ws + LOGNUM_OFF + (size_t)bhw*(NC*NO);
    float tmax = -3.0e38f;
    for (int it = 0; it < (NC*NO)/256/32*32/ (32/32); ) { break; }  // (dead; keep loop below simple)
    for (int it = 0; it < 36; ++it) {
        const int c = it*8 + (t >> 5);
        const float4* v4 = (const float4*)(vb + (size_t)c*CSTR + o*NA);
        float acc = 0.f;
        #pragma unroll
        for (int q = 0; q < 4; ++q) {
            float4 v = v4[q];
            float d0 = v.x - mur[q*4+0]; acc = fmaf(d0*d0, wr[q*4+0], acc);
            float d1 = v.y - mur[q*4+1]; acc = fmaf(d1*d1, wr[q*4+1], acc);
            float d2 = v.z - mur[q*4+2]; acc = fmaf(d2*d2, wr[q*4+2], acc);
            float d3 = v.w - mur[q*4+3]; acc = fmaf(d3*d3, wr[q*4+3], acc);
        }
        float ln = L - acc;
        lp[c*32 + o] = ln;                       // flat = it*256+t, coalesced
        tmax = fmaxf(tmax, ln);
    }
    #pragma unroll
    for (int d = 1; d < 64; d <<= 1) tmax = fmaxf(tmax, __shfl_xor(tmax, d));
    __shared__ float smax[4];
    if ((t & 63) == 0) smax[t >> 6] = tmax;
    __syncthreads();
    if (t == 0)
        ws[BM_OFF + bhw] = fmaxf(fmaxf(smax[0], smax[1]), fmaxf(smax[2], smax[3]));
}

// ---------------- Kernel Bmax: reduce 288 block maxes -> scalar ----------------
__global__ __launch_bounds__(256) void kBmax(float* __restrict__ ws) {
    const int t = threadIdx.x;
    float m = -3.0e38f;
    for (int i = t; i < NBHW; i += 256) m = fmaxf(m, ws[BM_OFF + i]);
    #pragma unroll
    for (int d = 1; d < 64; d <<= 1) m = fmaxf(m, __shfl_xor(m, d));
    __shared__ float sm[4];
    if ((t & 63) == 0) sm[t >> 6] = m;
    __syncthreads();
    if (t == 0) ws[M_OFF] = fmaxf(fmaxf(sm[0], sm[1]), fmaxf(sm[2], sm[3]));
}

// ---------------- Kernel C: ap summed over o, scattered to dense grid ----------------
// grid = NBHW, block = 256
__global__ __launch_bounds__(256) void kC(float* __restrict__ ws) {
    const int bhw = blockIdx.x;
    const int t = threadIdx.x;
    const int b = bhw / (NH*NW);
    const int rem = bhw % (NH*NW);
    const int y = rem / NW, x = rem % NW;
    const float M = ws[M_OFF];
    const float* lp = ws + LOGNUM_OFF + (size_t)bhw*(NC*NO);
    float* dense = ws + DENSE_OFF;
    for (int c = t; c < NC; c += 256) {
        const float* l = lp + c*32;
        float s = 0.f;
        #pragma unroll
        for (int o = 0; o < 32; ++o) s += expf(l[o] - M);
        const int i = c & 31, kk = c >> 5;
        const int ky = kk / 3, kx = kk % 3;
        atomicAdd(&dense[((b*HR + y+ky)*WR + (x+kx))*NI + i], s);
    }
}

// ---------------- Kernel D: R = ap/(denom+eps); final m_step; write outputs ----------------
// grid = NBHW*2, block = 256, thread t = (o_loc<<4)|a
__global__ __launch_bounds__(256) void kD(const float* __restrict__ votes,
        const float* __restrict__ acts, const float* __restrict__ beta_a,
        const float* __restrict__ beta_u, const float* __restrict__ ws,
        float* __restrict__ out) {
    __shared__ float s_rd[NC];   // acts[c] / (denom[c] + eps)
    const int bid = blockIdx.x;
    const int bhw = bid >> 1;
    const int obase = (bid & 1) * 16;
    const int t = threadIdx.x;
    const int a = t & 15;
    const int o = obase + (t >> 4);
    const int b = bhw / (NH*NW);
    const int rem = bhw % (NH*NW);
    const int y = rem / NW, x = rem % NW;
    const float* dense = ws + DENSE_OFF;
    for (int c = t; c < NC; c += 256) {
        const int i = c & 31, kk = c >> 5;
        const int ky = kk / 3, kx = kk % 3;
        float dn = dense[((b*HR + y+ky)*WR + (x+kx))*NI + i];
        s_rd[c] = acts[bhw*NC + c] / (dn + EPSF);
    }
    __syncthreads();
    const float M = ws[M_OFF];
    const float* lp = ws + LOGNUM_OFF + (size_t)bhw*(NC*NO) + o;
    const float* vb = votes + (size_t)bhw*VPB + obase*NA;
    float s1 = 0.f, s2 = 0.f, sumR = 0.f;
    #pragma unroll 4
    for (int c = 0; c < NC; ++c) {
        float ap = expf(lp[c*32] - M);          // broadcast across a-lanes
        float ra = s_rd[c] * ap;
        float v  = vb[(size_t)c*CSTR + t];
        float rv = ra * v;
        s1 += rv;
        s2 = fmaf(rv, v, s2);
        sumR += ra;
    }
    float mu  = s1 / (sumR + EPSF);
    float sig = (s2 - mu*(2.f*s1 - mu*sumR)) / (sumR + EPSF) + MINVAR;
    out[bhw*512 + obase*16 + t] = mu;           // poses (b,h,w,o,a,a)
    float cost = (beta_u[o] - 0.5f*logf(sig + EPSF)) * sumR;
    #pragma unroll
    for (int d = 1; d < 16; d <<= 1) cost += __shfl_xor(cost, d);
    if (a == 0) {
        float aj = 1.0f/(1.0f + expf(-TEMPF*(beta_a[o] - cost)));
        out[NBHW*512 + bhw*32 + o] = aj;        // acts (b,h,w,o)
    }
}

extern "C" void kernel_launch(void* const* d_in, const int* in_sizes, int n_in,
                              void* d_out, int out_size, void* d_ws, size_t ws_size,
                              hipStream_t stream) {
    const float* votes  = (const float*)d_in[0];
    const float* acts   = (const float*)d_in[1];
    const float* beta_a = (const float*)d_in[2];
    const float* beta_u = (const float*)d_in[3];
    float* ws  = (float*)d_ws;
    float* out = (float*)d_out;

    hipMemsetAsync(ws + DENSE_OFF, 0, DENSE_N*sizeof(float), stream);
    kA   <<<NBHW*2, 256, 0, stream>>>(votes, acts, beta_a, beta_u, ws);
    kB   <<<NBHW,   256, 0, stream>>>(votes, ws);
    kBmax<<<1,      256, 0, stream>>>(ws);
    kC   <<<NBHW,   256, 0, stream>>>(ws);
    kD   <<<NBHW*2, 256, 0, stream>>>(votes, acts, beta_a, beta_u, ws, out);
}